// Round 6
// baseline (539.032 us; speedup 1.0000x reference)
//
#include <hip/hip_runtime.h>

#define H_  2048
#define BS_ 128
#define NB_ 44
#define R_  64
#define K_  8
#define N_  8192
#define I_  5632
#define MT  64
#define TILES 32
#define GRID_AB (8 * 6 * TILES)

typedef __bf16 bf16x8 __attribute__((ext_vector_type(8)));
typedef float  f32x4  __attribute__((ext_vector_type(4)));

__device__ __forceinline__ unsigned short f2bf(float f) {
  unsigned int u = __float_as_uint(f);
  u = (u + 0x7FFFu + ((u >> 16) & 1u)) >> 16;
  return (unsigned short)u;
}
__device__ __forceinline__ float bf2f(unsigned short s) {
  return __uint_as_float(((unsigned int)s) << 16);
}
__device__ __forceinline__ bf16x8 ld8(const unsigned short* p) {
  uint4 v = *reinterpret_cast<const uint4*>(p);
  return __builtin_bit_cast(bf16x8, v);
}
__device__ __forceinline__ bf16x8 lds8(const char* p) {
  uint4 v = *reinterpret_cast<const uint4*>(p);
  return __builtin_bit_cast(bf16x8, v);
}
__device__ __forceinline__ void gl16(const void* g, void* l) {
  __builtin_amdgcn_global_load_lds(
      (const __attribute__((address_space(1))) char*)g,
      (__attribute__((address_space(3))) char*)l, 16, 0, 0);
}

// ---------------- conversions ---------------------------------------------
__global__ void cvt_xgu(const float* __restrict__ x, const float* __restrict__ gw,
                        const float* __restrict__ uw, const float* __restrict__ ew,
                        unsigned short* __restrict__ xb,
                        unsigned short* __restrict__ gwb,
                        unsigned short* __restrict__ uwb,
                        unsigned short* __restrict__ ewb) {
  const int NX4 = N_ * H_ / 4;
  const int NG4 = I_ * H_ / 4;
  const int NE4 = R_ * H_ / 4;
  int total = NX4 + 2 * NG4 + NE4;
  int stride = gridDim.x * blockDim.x;
  for (int i = blockIdx.x * blockDim.x + threadIdx.x; i < total; i += stride) {
    const float4* s; ushort4* d; int j;
    if (i < NX4)                  { s = (const float4*)x;  d = (ushort4*)xb;  j = i; }
    else if (i < NX4 + NG4)       { s = (const float4*)gw; d = (ushort4*)gwb; j = i - NX4; }
    else if (i < NX4 + 2 * NG4)   { s = (const float4*)uw; d = (ushort4*)uwb; j = i - NX4 - NG4; }
    else                          { s = (const float4*)ew; d = (ushort4*)ewb; j = i - NX4 - 2 * NG4; }
    float4 v = s[j];
    ushort4 o; o.x = f2bf(v.x); o.y = f2bf(v.y); o.z = f2bf(v.z); o.w = f2bf(v.w);
    d[j] = o;
  }
}

// down_w [H][I] f32 -> dwb [NB][H][128] bf16
__global__ void cvt_down(const float* __restrict__ dw, unsigned short* __restrict__ dwb) {
  int total = H_ * I_ / 4;
  int stride = gridDim.x * blockDim.x;
  for (int i = blockIdx.x * blockDim.x + threadIdx.x; i < total; i += stride) {
    float4 v = ((const float4*)dw)[i];
    int flat = i * 4;
    int h = flat / I_;
    int rem = flat - h * I_;
    int b = rem >> 7, k = rem & 127;
    ushort4 o; o.x = f2bf(v.x); o.y = f2bf(v.y); o.z = f2bf(v.z); o.w = f2bf(v.w);
    *(ushort4*)(dwb + ((size_t)b * H_ + h) * BS_ + k) = o;
  }
}

// decoder [NB][R][BS] f32 -> dec_bf [NB][BS][R] bf16 (transposed)
__global__ void cvt_dec(const float* __restrict__ dec, unsigned short* __restrict__ decb) {
  int i = blockIdx.x * 256 + threadIdx.x;
  if (i >= NB_ * BS_ * R_) return;
  int b = i >> 13;
  int rem = i & 8191;
  int c = rem >> 6, r = rem & 63;
  decb[i] = f2bf(dec[(b << 13) + r * BS_ + c]);
}

// ---------------- routing prep --------------------------------------------
__global__ void zero_counts(int* __restrict__ counts) {
  if (threadIdx.x < NB_) counts[threadIdx.x] = 0;
}

__global__ void prep_kernel(const float* __restrict__ score,
                            const int* __restrict__ aidx,
                            float* __restrict__ w_buf,
                            int* __restrict__ counts) {
  __shared__ int hist[NB_];
  int tid = threadIdx.x;
  if (tid < NB_) hist[tid] = 0;
  __syncthreads();
  int n = blockIdx.x * 256 + tid;
  float s[K_];
  float m = -1e30f;
#pragma unroll
  for (int k = 0; k < K_; k++) { s[k] = score[n * K_ + k]; m = fmaxf(m, s[k]); }
  float sum = 0.f;
#pragma unroll
  for (int k = 0; k < K_; k++) { s[k] = __expf(s[k] - m); sum += s[k]; }
  float inv = 1.f / sum;
#pragma unroll
  for (int k = 0; k < K_; k++) {
    w_buf[n * K_ + k] = s[k] * inv;
    atomicAdd(&hist[aidx[n * K_ + k]], 1);
  }
  __syncthreads();
  if (tid < NB_) atomicAdd(&counts[tid], hist[tid]);
}

__global__ void scan_kernel(const int* __restrict__ counts,
                            int* __restrict__ offsets,
                            int* __restrict__ cursors) {
  if (threadIdx.x == 0) {
    int acc = 0;
    for (int b = 0; b < NB_; b++) { offsets[b] = acc; cursors[b] = acc; acc += counts[b]; }
    offsets[NB_] = acc;
  }
}

__global__ void fill_kernel(const int* __restrict__ aidx,
                            const float* __restrict__ w_buf,
                            int* __restrict__ cursors,
                            int* __restrict__ tok_list,
                            float* __restrict__ wt_list,
                            int* __restrict__ inv) {
  int n = blockIdx.x * 256 + threadIdx.x;
#pragma unroll
  for (int k = 0; k < K_; k++) {
    int b = aidx[n * K_ + k];
    int pos = atomicAdd(&cursors[b], 1);
    tok_list[pos] = n;
    wt_list[pos] = w_buf[n * K_ + k];
    inv[n * K_ + k] = pos;
  }
}

// ---------------- latent via MFMA -----------------------------------------
__global__ __launch_bounds__(256) void latent_mfma(
    const unsigned short* __restrict__ xb,
    const unsigned short* __restrict__ ewb,
    const float* __restrict__ enc_b,
    unsigned short* __restrict__ lat) {
  __shared__ __align__(16) char smem[16384];
  int tid = threadIdx.x;
  int wv = tid >> 6, lane = tid & 63;
  int lo = lane & 15, hi = lane >> 4;
  int n0 = blockIdx.x * 64;

  int rowA = tid >> 2;
  int jA = (tid & 3) ^ ((rowA >> 1) & 3);   // conflict-free swizzle
  const unsigned short* srcA = xb + (size_t)(n0 + rowA) * H_ + jA * 8;
  const unsigned short* srcB = ewb + (size_t)rowA * H_ + jA * 8;

  gl16(srcA, smem + wv * 1024);
  gl16(srcB, smem + 8192 + wv * 1024);
  __syncthreads();

  f32x4 acc[4] = {};
  int cur = 0;
  for (int ks = 0; ks < H_; ks += 32) {
    if (ks + 32 < H_) {
      gl16(srcA + ks + 32, smem + (cur ^ 1) * 4096 + wv * 1024);
      gl16(srcB + ks + 32, smem + 8192 + (cur ^ 1) * 4096 + wv * 1024);
    }
    int rB = wv * 16 + lo;
    bf16x8 Bf = lds8(smem + 8192 + cur * 4096 + (rB * 4 + (hi ^ ((rB >> 1) & 3))) * 16);
#pragma unroll
    for (int m = 0; m < 4; m++) {
      int row = m * 16 + lo;
      bf16x8 Af = lds8(smem + cur * 4096 + (row * 4 + (hi ^ ((row >> 1) & 3))) * 16);
      acc[m] = __builtin_amdgcn_mfma_f32_16x16x32_bf16(Af, Bf, acc[m], 0, 0, 0);
    }
    __syncthreads();
    cur ^= 1;
  }

  int r = wv * 16 + lo;
  float eb = enc_b[r];
#pragma unroll
  for (int m = 0; m < 4; m++) {
#pragma unroll
    for (int rg = 0; rg < 4; rg++) {
      int tok = n0 + m * 16 + hi * 4 + rg;
      float v = acc[m][rg] + eb;
      lat[(size_t)tok * R_ + r] = f2bf(v / (1.f + __expf(-v)));
    }
  }
}

__device__ __forceinline__ bool decode_bt(int p, int& b, int& tile) {
  b = (p & 7) + 8 * ((p >> 3) / TILES);
  tile = (p >> 3) % TILES;
  return b < NB_;
}

// ---------------- gateup: pipelined LDS GEMM + MFMA comp ------------------
__global__ __launch_bounds__(256, 3) void gateup_kernel(
    const unsigned short* __restrict__ xb,
    const unsigned short* __restrict__ gwb,
    const unsigned short* __restrict__ uwb,
    const unsigned short* __restrict__ latb,
    const unsigned short* __restrict__ decb_all,
    const float* __restrict__ bbias,
    const float* __restrict__ scale_p,
    const int* __restrict__ counts,
    const int* __restrict__ offsets,
    const int* __restrict__ tok_list,
    const float* __restrict__ wt_list,
    unsigned short* __restrict__ actw) {
  int b, tile;
  if (!decode_bt(blockIdx.x, b, tile)) return;
  int cnt = counts[b];
  int base = tile * MT;
  if (base >= cnt) return;
  int off = offsets[b];

  __shared__ __align__(16) char smem[40960];
  __shared__ float wt_lds[MT];

  int tid = threadIdx.x;
  int wv = tid >> 6, lane = tid & 63;
  int lo = lane & 15, hi = lane >> 4;

  if (tid < MT) {
    int g = base + tid;
    wt_lds[tid] = (g < cnt) ? wt_list[off + g] : 0.f;
  }

  int rowA = tid >> 2;
  int jA = (tid & 3) ^ ((rowA >> 1) & 3);   // conflict-free swizzle
  int tokA = tok_list[off + min(base + rowA, cnt - 1)];
  const unsigned short* srcA = xb + (size_t)tokA * H_ + jA * 8;

  const unsigned short* gb = gwb + (size_t)b * BS_ * H_;
  const unsigned short* ub = uwb + (size_t)b * BS_ * H_;
  const unsigned short* srcG[2];
  const unsigned short* srcU[2];
#pragma unroll
  for (int s = 0; s < 2; s++) {
    int o = s * 256 + tid;
    int c = o >> 2;
    int j = (o & 3) ^ ((c >> 1) & 3);       // conflict-free swizzle
    size_t e = (size_t)c * H_ + j * 8;
    srcG[s] = gb + e;
    srcU[s] = ub + e;
  }

  f32x4 accG[4][2] = {};
  f32x4 accU[4][2] = {};

  {
    gl16(srcA, smem + wv * 1024);
#pragma unroll
    for (int s = 0; s < 2; s++) {
      gl16(srcG[s], smem + 8192 + s * 4096 + wv * 1024);
      gl16(srcU[s], smem + 24576 + s * 4096 + wv * 1024);
    }
  }
  __syncthreads();

  int cur = 0;
  for (int ks = 0; ks < H_; ks += 32) {
    if (ks + 32 < H_) {
      int nb_ = cur ^ 1;
      gl16(srcA + ks + 32, smem + nb_ * 4096 + wv * 1024);
#pragma unroll
      for (int s = 0; s < 2; s++) {
        gl16(srcG[s] + ks + 32, smem + 8192 + nb_ * 8192 + s * 4096 + wv * 1024);
        gl16(srcU[s] + ks + 32, smem + 24576 + nb_ * 8192 + s * 4096 + wv * 1024);
      }
    }
    bf16x8 Af[4];
#pragma unroll
    for (int m = 0; m < 4; m++) {
      int row = m * 16 + lo;
      int off16 = row * 4 + (hi ^ ((row >> 1) & 3));
      Af[m] = lds8(smem + cur * 4096 + off16 * 16);
    }
    bf16x8 Gf[2], Uf[2];
#pragma unroll
    for (int cf = 0; cf < 2; cf++) {
      int c = wv * 32 + cf * 16 + lo;
      int off16 = c * 4 + (hi ^ ((c >> 1) & 3));
      Gf[cf] = lds8(smem + 8192 + cur * 8192 + off16 * 16);
      Uf[cf] = lds8(smem + 24576 + cur * 8192 + off16 * 16);
    }
#pragma unroll
    for (int m = 0; m < 4; m++) {
#pragma unroll
      for (int cf = 0; cf < 2; cf++) {
        accG[m][cf] = __builtin_amdgcn_mfma_f32_16x16x32_bf16(Af[m], Gf[cf], accG[m][cf], 0, 0, 0);
        accU[m][cf] = __builtin_amdgcn_mfma_f32_16x16x32_bf16(Af[m], Uf[cf], accU[m][cf], 0, 0, 0);
      }
    }
    __syncthreads();
    cur ^= 1;
  }

  // ---- comp GEMM (K=64) ---- (row&7 chunk swizzle: already conflict-free)
#pragma unroll
  for (int s = 0; s < 2; s++) {
    int o = s * 256 + tid;
    int r_ = o >> 3;
    int j = (o & 7) ^ (r_ & 7);
    int tokL = tok_list[off + min(base + r_, cnt - 1)];
    gl16(latb + (size_t)tokL * R_ + j * 8, smem + 24576 + s * 4096 + wv * 1024);
  }
  const unsigned short* decb = decb_all + (size_t)b * BS_ * R_;
#pragma unroll
  for (int s = 0; s < 4; s++) {
    int o = s * 256 + tid;
    int c = o >> 3;
    int j = (o & 7) ^ (c & 7);
    gl16(decb + (size_t)c * R_ + j * 8, smem + 8192 + s * 4096 + wv * 1024);
  }
  __syncthreads();

  f32x4 accC[4][2] = {};
#pragma unroll
  for (int kk = 0; kk < 2; kk++) {
    bf16x8 L[4];
#pragma unroll
    for (int m = 0; m < 4; m++) {
      int row = m * 16 + lo;
      int off16 = row * 8 + ((kk * 4 + hi) ^ (lo & 7));
      L[m] = lds8(smem + 24576 + off16 * 16);
    }
#pragma unroll
    for (int cf = 0; cf < 2; cf++) {
      int c = wv * 32 + cf * 16 + lo;
      int off16 = c * 8 + ((kk * 4 + hi) ^ (lo & 7));
      bf16x8 D = lds8(smem + 8192 + off16 * 16);
#pragma unroll
      for (int m = 0; m < 4; m++)
        accC[m][cf] = __builtin_amdgcn_mfma_f32_16x16x32_bf16(L[m], D, accC[m][cf], 0, 0, 0);
    }
  }

  float scal = scale_p[0];
  int cc[2] = { wv * 32 + lo, wv * 32 + 16 + lo };
  float bbv[2] = { bbias[b * BS_ + cc[0]], bbias[b * BS_ + cc[1]] };
#pragma unroll
  for (int m = 0; m < 4; m++) {
#pragma unroll
    for (int r = 0; r < 4; r++) {
      int t = m * 16 + hi * 4 + r;
      int g = base + t;
      if (g < cnt) {
        float wt = wt_lds[t];
        unsigned short* dst = actw + (size_t)(off + g) * BS_;
#pragma unroll
        for (int cf = 0; cf < 2; cf++) {
          float gg = accG[m][cf][r];
          float uu = accU[m][cf][r];
          float act = (gg / (1.f + __expf(-gg))) * uu;
          dst[cc[cf]] = f2bf((act + scal * (accC[m][cf][r] + bbv[cf])) * wt);
        }
      }
    }
  }
}

// ---------------- down: LDS-staged B, reg-cached act, chunked H -----------
__global__ __launch_bounds__(256) void down_kernel(
    const unsigned short* __restrict__ actw,
    const unsigned short* __restrict__ dwb,
    const int* __restrict__ counts,
    const int* __restrict__ offsets,
    unsigned short* __restrict__ partial,
    int hc0, int Hc) {
  int b, tile;
  if (!decode_bt(blockIdx.x, b, tile)) return;
  int cnt = counts[b];
  int base = tile * MT;
  if (base >= cnt) return;
  int off = offsets[b];

  __shared__ __align__(16) unsigned short a_lds[MT * BS_];
  __shared__ __align__(16) char b_lds[2][16384];
  int tid = threadIdx.x;
  int wv = tid >> 6, lane = tid & 63;
  int lo = lane & 15, hi = lane >> 4;

  for (int i = tid; i < MT * BS_ / 8; i += 256) {
    int t = i >> 4, cb = i & 15;
    int g = base + t;
    uint4 v = make_uint4(0, 0, 0, 0);
    if (g < cnt) v = *(const uint4*)(actw + (size_t)(off + g) * BS_ + cb * 8);
    *(uint4*)(&a_lds[t * BS_ + ((cb ^ (t & 7)) << 3)]) = v;
  }
  __syncthreads();

  bf16x8 Bf[4][4];
#pragma unroll
  for (int kst = 0; kst < 4; kst++)
#pragma unroll
    for (int sf = 0; sf < 4; sf++) {
      int t = sf * 16 + lo, cb = kst * 4 + hi;
      Bf[kst][sf] = ld8(&a_lds[t * BS_ + ((cb ^ (t & 7)) << 3)]);
    }

  const unsigned short* db = dwb + (size_t)b * H_ * BS_;
  int rs = tid >> 4;
  int jc = tid & 15;
  {
    const unsigned short* d0 = db + (size_t)hc0 * BS_;
#pragma unroll
    for (int s = 0; s < 4; s++) {
      int r = s * 16 + rs;
      int j = jc ^ (r & 15);
      gl16(d0 + (size_t)r * BS_ + j * 8, b_lds[0] + s * 4096 + wv * 1024);
    }
  }
  __syncthreads();

  int nit = Hc >> 6;
  int cur = 0;
  for (int it = 0; it < nit; it++) {
    if (it + 1 < nit) {
      const unsigned short* dn = db + (size_t)(hc0 + (it + 1) * 64) * BS_;
#pragma unroll
      for (int s = 0; s < 4; s++) {
        int r = s * 16 + rs;
        int j = jc ^ (r & 15);
        gl16(dn + (size_t)r * BS_ + j * 8, b_lds[cur ^ 1] + s * 4096 + wv * 1024);
      }
    }
    f32x4 acc[4] = {};
    int rl = wv * 16 + lo;
#pragma unroll
    for (int kst = 0; kst < 4; kst++) {
      int cb = kst * 4 + hi;
      bf16x8 Aw = lds8(b_lds[cur] + (rl * 16 + (cb ^ lo)) * 16);
#pragma unroll
      for (int sf = 0; sf < 4; sf++)
        acc[sf] = __builtin_amdgcn_mfma_f32_16x16x32_bf16(Aw, Bf[kst][sf], acc[sf], 0, 0, 0);
    }
    int hrel = it * 64 + wv * 16 + hi * 4;
#pragma unroll
    for (int sf = 0; sf < 4; sf++) {
      int g = base + sf * 16 + lo;
      if (g < cnt) {
        uint2 pk;
        pk.x = (unsigned int)f2bf(acc[sf][0]) | ((unsigned int)f2bf(acc[sf][1]) << 16);
        pk.y = (unsigned int)f2bf(acc[sf][2]) | ((unsigned int)f2bf(acc[sf][3]) << 16);
        *(uint2*)(partial + (size_t)(off + g) * Hc + hrel) = pk;
      }
    }
    __syncthreads();
    cur ^= 1;
  }
}

// ---------------- reduce ---------------------------------------------------
__global__ __launch_bounds__(256) void reduce_kernel(
    const unsigned short* __restrict__ partial,
    const int* __restrict__ inv,
    const float* __restrict__ cbias,
    float* __restrict__ out, int hc0, int Hc) {
  int wv = threadIdx.x >> 6, l = threadIdx.x & 63;
  int n = blockIdx.x * 4 + wv;
  int rows[K_];
#pragma unroll
  for (int k = 0; k < K_; k++) rows[k] = inv[n * K_ + k];
  for (int c0w = 0; c0w < Hc; c0w += 512) {
    int cw = c0w + l * 8;
    if (cw >= Hc) continue;
    float a[8] = {0.f, 0.f, 0.f, 0.f, 0.f, 0.f, 0.f, 0.f};
#pragma unroll
    for (int k = 0; k < K_; k++) {
      uint4 v = *(const uint4*)(partial + (size_t)rows[k] * Hc + cw);
      unsigned int w0 = v.x, w1 = v.y, w2 = v.z, w3 = v.w;
      a[0] += __uint_as_float(w0 << 16); a[1] += __uint_as_float(w0 & 0xFFFF0000u);
      a[2] += __uint_as_float(w1 << 16); a[3] += __uint_as_float(w1 & 0xFFFF0000u);
      a[4] += __uint_as_float(w2 << 16); a[5] += __uint_as_float(w2 & 0xFFFF0000u);
      a[6] += __uint_as_float(w3 << 16); a[7] += __uint_as_float(w3 & 0xFFFF0000u);
    }
    int h = hc0 + cw;
    float4 c0 = *(const float4*)(cbias + h);
    float4 c1 = *(const float4*)(cbias + h + 4);
    float4 o0 = make_float4(a[0] + c0.x, a[1] + c0.y, a[2] + c0.z, a[3] + c0.w);
    float4 o1 = make_float4(a[4] + c1.x, a[5] + c1.y, a[6] + c1.z, a[7] + c1.w);
    *(float4*)(out + (size_t)n * H_ + h) = o0;
    *(float4*)(out + (size_t)n * H_ + h + 4) = o1;
  }
}

// ---------------- launch ---------------------------------------------------
extern "C" void kernel_launch(void* const* d_in, const int* in_sizes, int n_in,
                              void* d_out, int out_size, void* d_ws, size_t ws_size,
                              hipStream_t stream) {
  const float* x       = (const float*)d_in[0];
  const int*   aidx    = (const int*)d_in[1];
  const float* score   = (const float*)d_in[2];
  const float* gate_w  = (const float*)d_in[3];
  const float* up_w    = (const float*)d_in[4];
  const float* down_w  = (const float*)d_in[5];
  const float* enc_w   = (const float*)d_in[6];
  const float* enc_b   = (const float*)d_in[7];
  const float* decoder = (const float*)d_in[8];
  const float* bbias   = (const float*)d_in[9];
  const float* cbias   = (const float*)d_in[10];
  const float* scale   = (const float*)d_in[11];
  float* out = (float*)d_out;

  char* ws = (char*)d_ws;
  const size_t OFF_GWB  = 33554432ull;
  const size_t OFF_UWB  = 56623104ull;
  const size_t OFF_DEC  = 79691776ull;
  const size_t OFF_LATB = 80412672ull;
  const size_t OFF_ENCB = 81461248ull;
  const size_t OFF_WBUF = 81723392ull;
  const size_t OFF_TOK  = 81985536ull;
  const size_t OFF_WT   = 82247680ull;
  const size_t OFF_INV  = 82509824ull;
  const size_t OFF_CNT  = 82771968ull;
  const size_t OFF_ACTW = 82772992ull;
  const size_t BASE_END = 99550208ull;
  const size_t DWB_SZ   = 23068672ull;

  unsigned short* xb   = (unsigned short*)(ws);
  unsigned short* gwb  = (unsigned short*)(ws + OFF_GWB);
  unsigned short* uwb  = (unsigned short*)(ws + OFF_UWB);
  unsigned short* decb = (unsigned short*)(ws + OFF_DEC);
  unsigned short* latb = (unsigned short*)(ws + OFF_LATB);
  unsigned short* ewb  = (unsigned short*)(ws + OFF_ENCB);
  float* w_buf         = (float*)(ws + OFF_WBUF);
  int*   tok_list      = (int*)(ws + OFF_TOK);
  float* wt_list       = (float*)(ws + OFF_WT);
  int*   inv           = (int*)(ws + OFF_INV);
  int*   counts        = (int*)(ws + OFF_CNT);
  int*   offsets       = counts + 64;
  int*   cursors       = counts + 128;
  unsigned short* actw = (unsigned short*)(ws + OFF_ACTW);

  int Hc; unsigned short* dwb; unsigned short* partial; bool early_down;
  if      (ws_size >= BASE_END + DWB_SZ + 131072ull * 512) Hc = 512;
  else if (ws_size >= BASE_END + DWB_SZ + 131072ull * 256) Hc = 256;
  else Hc = 0;
  if (Hc) {
    early_down = true;
    dwb = (unsigned short*)(ws + BASE_END);
    partial = (unsigned short*)(ws + BASE_END + DWB_SZ);
  } else {
    early_down = false;
    Hc = 256;
    dwb = gwb;
    partial = (unsigned short*)ws;
  }
  int nch = H_ / Hc;

  cvt_xgu<<<2048, 256, 0, stream>>>(x, gate_w, up_w, enc_w, xb, gwb, uwb, ewb);
  cvt_dec<<<(NB_ * BS_ * R_ + 255) / 256, 256, 0, stream>>>(decoder, decb);
  if (early_down) cvt_down<<<2048, 256, 0, stream>>>(down_w, dwb);
  zero_counts<<<1, 64, 0, stream>>>(counts);
  prep_kernel<<<N_ / 256, 256, 0, stream>>>(score, aidx, w_buf, counts);
  scan_kernel<<<1, 64, 0, stream>>>(counts, offsets, cursors);
  fill_kernel<<<N_ / 256, 256, 0, stream>>>(aidx, w_buf, cursors, tok_list, wt_list, inv);
  latent_mfma<<<N_ / 64, 256, 0, stream>>>(xb, ewb, enc_b, latb);
  gateup_kernel<<<GRID_AB, 256, 0, stream>>>(xb, gwb, uwb, latb, decb, bbias, scale,
                                             counts, offsets, tok_list, wt_list, actw);
  if (!early_down) cvt_down<<<2048, 256, 0, stream>>>(down_w, dwb);
  for (int c = 0; c < nch; c++) {
    down_kernel<<<GRID_AB, 256, 0, stream>>>(actw, dwb, counts, offsets, partial, c * Hc, Hc);
    reduce_kernel<<<N_ / 4, 256, 0, stream>>>(partial, inv, cbias, out, c * Hc, Hc);
  }
}

// Round 7
// 533.769 us; speedup vs baseline: 1.0099x; 1.0099x over previous
//
#include <hip/hip_runtime.h>

#define H_  2048
#define BS_ 128
#define NB_ 44
#define R_  64
#define K_  8
#define N_  8192
#define I_  5632
#define MT  64
#define TILES 32
#define GRID_AB (8 * 6 * TILES)

typedef __bf16 bf16x8 __attribute__((ext_vector_type(8)));
typedef float  f32x4  __attribute__((ext_vector_type(4)));

__device__ __forceinline__ unsigned short f2bf(float f) {
  unsigned int u = __float_as_uint(f);
  u = (u + 0x7FFFu + ((u >> 16) & 1u)) >> 16;
  return (unsigned short)u;
}
__device__ __forceinline__ float bf2f(unsigned short s) {
  return __uint_as_float(((unsigned int)s) << 16);
}
__device__ __forceinline__ bf16x8 ld8(const unsigned short* p) {
  uint4 v = *reinterpret_cast<const uint4*>(p);
  return __builtin_bit_cast(bf16x8, v);
}
__device__ __forceinline__ bf16x8 lds8(const char* p) {
  uint4 v = *reinterpret_cast<const uint4*>(p);
  return __builtin_bit_cast(bf16x8, v);
}
__device__ __forceinline__ void gl16(const void* g, void* l) {
  __builtin_amdgcn_global_load_lds(
      (const __attribute__((address_space(1))) char*)g,
      (__attribute__((address_space(3))) char*)l, 16, 0, 0);
}
#define WAIT_VM(n) do { asm volatile("s_waitcnt vmcnt(" #n ")" ::: "memory"); \
                        __builtin_amdgcn_sched_barrier(0); } while (0)
#define WAIT_LGKM0 do { asm volatile("s_waitcnt lgkmcnt(0)" ::: "memory"); \
                        __builtin_amdgcn_sched_barrier(0); } while (0)
#define SBAR __builtin_amdgcn_s_barrier()

// ---------------- conversions ---------------------------------------------
__global__ void cvt_xgu(const float* __restrict__ x, const float* __restrict__ gw,
                        const float* __restrict__ uw, const float* __restrict__ ew,
                        unsigned short* __restrict__ xb,
                        unsigned short* __restrict__ gwb,
                        unsigned short* __restrict__ uwb,
                        unsigned short* __restrict__ ewb) {
  const int NX4 = N_ * H_ / 4;
  const int NG4 = I_ * H_ / 4;
  const int NE4 = R_ * H_ / 4;
  int total = NX4 + 2 * NG4 + NE4;
  int stride = gridDim.x * blockDim.x;
  for (int i = blockIdx.x * blockDim.x + threadIdx.x; i < total; i += stride) {
    const float4* s; ushort4* d; int j;
    if (i < NX4)                  { s = (const float4*)x;  d = (ushort4*)xb;  j = i; }
    else if (i < NX4 + NG4)       { s = (const float4*)gw; d = (ushort4*)gwb; j = i - NX4; }
    else if (i < NX4 + 2 * NG4)   { s = (const float4*)uw; d = (ushort4*)uwb; j = i - NX4 - NG4; }
    else                          { s = (const float4*)ew; d = (ushort4*)ewb; j = i - NX4 - 2 * NG4; }
    float4 v = s[j];
    ushort4 o; o.x = f2bf(v.x); o.y = f2bf(v.y); o.z = f2bf(v.z); o.w = f2bf(v.w);
    d[j] = o;
  }
}

// down_w [H][I] f32 -> dwb [NB][H][128] bf16
__global__ void cvt_down(const float* __restrict__ dw, unsigned short* __restrict__ dwb) {
  int total = H_ * I_ / 4;
  int stride = gridDim.x * blockDim.x;
  for (int i = blockIdx.x * blockDim.x + threadIdx.x; i < total; i += stride) {
    float4 v = ((const float4*)dw)[i];
    int flat = i * 4;
    int h = flat / I_;
    int rem = flat - h * I_;
    int b = rem >> 7, k = rem & 127;
    ushort4 o; o.x = f2bf(v.x); o.y = f2bf(v.y); o.z = f2bf(v.z); o.w = f2bf(v.w);
    *(ushort4*)(dwb + ((size_t)b * H_ + h) * BS_ + k) = o;
  }
}

// decoder [NB][R][BS] f32 -> dec_bf [NB][BS][R] bf16 (transposed)
__global__ void cvt_dec(const float* __restrict__ dec, unsigned short* __restrict__ decb) {
  int i = blockIdx.x * 256 + threadIdx.x;
  if (i >= NB_ * BS_ * R_) return;
  int b = i >> 13;
  int rem = i & 8191;
  int c = rem >> 6, r = rem & 63;
  decb[i] = f2bf(dec[(b << 13) + r * BS_ + c]);
}

// ---------------- routing prep --------------------------------------------
__global__ void zero_counts(int* __restrict__ counts) {
  if (threadIdx.x < NB_) counts[threadIdx.x] = 0;
}

__global__ void prep_kernel(const float* __restrict__ score,
                            const int* __restrict__ aidx,
                            float* __restrict__ w_buf,
                            int* __restrict__ counts) {
  __shared__ int hist[NB_];
  int tid = threadIdx.x;
  if (tid < NB_) hist[tid] = 0;
  __syncthreads();
  int n = blockIdx.x * 256 + tid;
  float s[K_];
  float m = -1e30f;
#pragma unroll
  for (int k = 0; k < K_; k++) { s[k] = score[n * K_ + k]; m = fmaxf(m, s[k]); }
  float sum = 0.f;
#pragma unroll
  for (int k = 0; k < K_; k++) { s[k] = __expf(s[k] - m); sum += s[k]; }
  float inv = 1.f / sum;
#pragma unroll
  for (int k = 0; k < K_; k++) {
    w_buf[n * K_ + k] = s[k] * inv;
    atomicAdd(&hist[aidx[n * K_ + k]], 1);
  }
  __syncthreads();
  if (tid < NB_) atomicAdd(&counts[tid], hist[tid]);
}

__global__ void scan_kernel(const int* __restrict__ counts,
                            int* __restrict__ offsets,
                            int* __restrict__ cursors) {
  if (threadIdx.x == 0) {
    int acc = 0;
    for (int b = 0; b < NB_; b++) { offsets[b] = acc; cursors[b] = acc; acc += counts[b]; }
    offsets[NB_] = acc;
  }
}

__global__ void fill_kernel(const int* __restrict__ aidx,
                            const float* __restrict__ w_buf,
                            int* __restrict__ cursors,
                            int* __restrict__ tok_list,
                            float* __restrict__ wt_list,
                            int* __restrict__ inv) {
  int n = blockIdx.x * 256 + threadIdx.x;
#pragma unroll
  for (int k = 0; k < K_; k++) {
    int b = aidx[n * K_ + k];
    int pos = atomicAdd(&cursors[b], 1);
    tok_list[pos] = n;
    wt_list[pos] = w_buf[n * K_ + k];
    inv[n * K_ + k] = pos;
  }
}

// ---------------- latent via MFMA (counted-vmcnt pipeline) ----------------
__global__ __launch_bounds__(256) void latent_mfma(
    const unsigned short* __restrict__ xb,
    const unsigned short* __restrict__ ewb,
    const float* __restrict__ enc_b,
    unsigned short* __restrict__ lat) {
  __shared__ __align__(16) char smem[16384];
  int tid = threadIdx.x;
  int wv = tid >> 6, lane = tid & 63;
  int lo = lane & 15, hi = lane >> 4;
  int n0 = blockIdx.x * 64;

  int rowA = tid >> 2;
  int jA = (tid & 3) ^ ((rowA >> 1) & 3);
  const unsigned short* srcA = xb + (size_t)(n0 + rowA) * H_ + jA * 8;
  const unsigned short* srcB = ewb + (size_t)rowA * H_ + jA * 8;

  gl16(srcA, smem + wv * 1024);
  gl16(srcB, smem + 8192 + wv * 1024);

  f32x4 acc[4] = {};
  int cur = 0;
  for (int ks = 0; ks < H_; ks += 32) {
    if (ks + 32 < H_) {
      gl16(srcA + ks + 32, smem + (cur ^ 1) * 4096 + wv * 1024);
      gl16(srcB + ks + 32, smem + 8192 + (cur ^ 1) * 4096 + wv * 1024);
      WAIT_VM(2);
    } else {
      WAIT_VM(0);
    }
    SBAR;
    int rB = wv * 16 + lo;
    bf16x8 Bf = lds8(smem + 8192 + cur * 4096 + (rB * 4 + (hi ^ ((rB >> 1) & 3))) * 16);
#pragma unroll
    for (int m = 0; m < 4; m++) {
      int row = m * 16 + lo;
      bf16x8 Af = lds8(smem + cur * 4096 + (row * 4 + (hi ^ ((row >> 1) & 3))) * 16);
      acc[m] = __builtin_amdgcn_mfma_f32_16x16x32_bf16(Af, Bf, acc[m], 0, 0, 0);
    }
    WAIT_LGKM0;
    SBAR;
    cur ^= 1;
  }

  int r = wv * 16 + lo;
  float eb = enc_b[r];
#pragma unroll
  for (int m = 0; m < 4; m++) {
#pragma unroll
    for (int rg = 0; rg < 4; rg++) {
      int tok = n0 + m * 16 + hi * 4 + rg;
      float v = acc[m][rg] + eb;
      lat[(size_t)tok * R_ + r] = f2bf(v / (1.f + __expf(-v)));
    }
  }
}

__device__ __forceinline__ bool decode_bt(int p, int& b, int& tile) {
  b = (p & 7) + 8 * ((p >> 3) / TILES);
  tile = (p >> 3) % TILES;
  return b < NB_;
}

// ---------------- gateup: counted-vmcnt pipelined GEMM + MFMA comp --------
__global__ __launch_bounds__(256, 3) void gateup_kernel(
    const unsigned short* __restrict__ xb,
    const unsigned short* __restrict__ gwb,
    const unsigned short* __restrict__ uwb,
    const unsigned short* __restrict__ latb,
    const unsigned short* __restrict__ decb_all,
    const float* __restrict__ bbias,
    const float* __restrict__ scale_p,
    const int* __restrict__ counts,
    const int* __restrict__ offsets,
    const int* __restrict__ tok_list,
    const float* __restrict__ wt_list,
    unsigned short* __restrict__ actw) {
  int b, tile;
  if (!decode_bt(blockIdx.x, b, tile)) return;
  int cnt = counts[b];
  int base = tile * MT;
  if (base >= cnt) return;
  int off = offsets[b];

  __shared__ __align__(16) char smem[40960];
  __shared__ float wt_lds[MT];

  int tid = threadIdx.x;
  int wv = tid >> 6, lane = tid & 63;
  int lo = lane & 15, hi = lane >> 4;

  if (tid < MT) {
    int g = base + tid;
    wt_lds[tid] = (g < cnt) ? wt_list[off + g] : 0.f;
  }

  int rowA = tid >> 2;
  int jA = (tid & 3) ^ ((rowA >> 1) & 3);
  int tokA = tok_list[off + min(base + rowA, cnt - 1)];
  const unsigned short* srcA = xb + (size_t)tokA * H_ + jA * 8;

  const unsigned short* gb = gwb + (size_t)b * BS_ * H_;
  const unsigned short* ub = uwb + (size_t)b * BS_ * H_;
  const unsigned short* srcG[2];
  const unsigned short* srcU[2];
#pragma unroll
  for (int s = 0; s < 2; s++) {
    int o = s * 256 + tid;
    int c = o >> 2;
    int j = (o & 3) ^ ((c >> 1) & 3);
    size_t e = (size_t)c * H_ + j * 8;
    srcG[s] = gb + e;
    srcU[s] = ub + e;
  }

  f32x4 accG[4][2] = {};
  f32x4 accU[4][2] = {};

  // prologue: issue stage of buf0 (5 gl16), no drain
  gl16(srcA, smem + wv * 1024);
#pragma unroll
  for (int s = 0; s < 2; s++) {
    gl16(srcG[s], smem + 8192 + s * 4096 + wv * 1024);
    gl16(srcU[s], smem + 24576 + s * 4096 + wv * 1024);
  }

  int cur = 0;
  for (int ks = 0; ks < H_; ks += 32) {
    if (ks + 32 < H_) {
      int nb_ = cur ^ 1;
      gl16(srcA + ks + 32, smem + nb_ * 4096 + wv * 1024);
#pragma unroll
      for (int s = 0; s < 2; s++) {
        gl16(srcG[s] + ks + 32, smem + 8192 + nb_ * 8192 + s * 4096 + wv * 1024);
        gl16(srcU[s] + ks + 32, smem + 24576 + nb_ * 8192 + s * 4096 + wv * 1024);
      }
      WAIT_VM(5);            // prev stage complete; new 5 stay in flight
    } else {
      WAIT_VM(0);
    }
    SBAR;                    // all waves' cur-buffer data visible
    bf16x8 Af[4];
#pragma unroll
    for (int m = 0; m < 4; m++) {
      int row = m * 16 + lo;
      int off16 = row * 4 + (hi ^ ((row >> 1) & 3));
      Af[m] = lds8(smem + cur * 4096 + off16 * 16);
    }
    bf16x8 Gf[2], Uf[2];
#pragma unroll
    for (int cf = 0; cf < 2; cf++) {
      int c = wv * 32 + cf * 16 + lo;
      int off16 = c * 4 + (hi ^ ((c >> 1) & 3));
      Gf[cf] = lds8(smem + 8192 + cur * 8192 + off16 * 16);
      Uf[cf] = lds8(smem + 24576 + cur * 8192 + off16 * 16);
    }
#pragma unroll
    for (int m = 0; m < 4; m++) {
#pragma unroll
      for (int cf = 0; cf < 2; cf++) {
        accG[m][cf] = __builtin_amdgcn_mfma_f32_16x16x32_bf16(Af[m], Gf[cf], accG[m][cf], 0, 0, 0);
        accU[m][cf] = __builtin_amdgcn_mfma_f32_16x16x32_bf16(Af[m], Uf[cf], accU[m][cf], 0, 0, 0);
      }
    }
    WAIT_LGKM0;              // this wave's ds_reads of cur have landed
    SBAR;                    // next iter may overwrite cur
    cur ^= 1;
  }

  // ---- comp GEMM (K=64) ----
#pragma unroll
  for (int s = 0; s < 2; s++) {
    int o = s * 256 + tid;
    int r_ = o >> 3;
    int j = (o & 7) ^ (r_ & 7);
    int tokL = tok_list[off + min(base + r_, cnt - 1)];
    gl16(latb + (size_t)tokL * R_ + j * 8, smem + 24576 + s * 4096 + wv * 1024);
  }
  const unsigned short* decb = decb_all + (size_t)b * BS_ * R_;
#pragma unroll
  for (int s = 0; s < 4; s++) {
    int o = s * 256 + tid;
    int c = o >> 3;
    int j = (o & 7) ^ (c & 7);
    gl16(decb + (size_t)c * R_ + j * 8, smem + 8192 + s * 4096 + wv * 1024);
  }
  __syncthreads();

  f32x4 accC[4][2] = {};
#pragma unroll
  for (int kk = 0; kk < 2; kk++) {
    bf16x8 L[4];
#pragma unroll
    for (int m = 0; m < 4; m++) {
      int row = m * 16 + lo;
      int off16 = row * 8 + ((kk * 4 + hi) ^ (lo & 7));
      L[m] = lds8(smem + 24576 + off16 * 16);
    }
#pragma unroll
    for (int cf = 0; cf < 2; cf++) {
      int c = wv * 32 + cf * 16 + lo;
      int off16 = c * 8 + ((kk * 4 + hi) ^ (lo & 7));
      bf16x8 D = lds8(smem + 8192 + off16 * 16);
#pragma unroll
      for (int m = 0; m < 4; m++)
        accC[m][cf] = __builtin_amdgcn_mfma_f32_16x16x32_bf16(L[m], D, accC[m][cf], 0, 0, 0);
    }
  }

  float scal = scale_p[0];
  int cc[2] = { wv * 32 + lo, wv * 32 + 16 + lo };
  float bbv[2] = { bbias[b * BS_ + cc[0]], bbias[b * BS_ + cc[1]] };
#pragma unroll
  for (int m = 0; m < 4; m++) {
#pragma unroll
    for (int r = 0; r < 4; r++) {
      int t = m * 16 + hi * 4 + r;
      int g = base + t;
      if (g < cnt) {
        float wt = wt_lds[t];
        unsigned short* dst = actw + (size_t)(off + g) * BS_;
#pragma unroll
        for (int cf = 0; cf < 2; cf++) {
          float gg = accG[m][cf][r];
          float uu = accU[m][cf][r];
          float act = (gg / (1.f + __expf(-gg))) * uu;
          dst[cc[cf]] = f2bf((act + scal * (accC[m][cf][r] + bbv[cf])) * wt);
        }
      }
    }
  }
}

// ---------------- down: LDS-staged B, reg-cached act, chunked H -----------
__global__ __launch_bounds__(256) void down_kernel(
    const unsigned short* __restrict__ actw,
    const unsigned short* __restrict__ dwb,
    const int* __restrict__ counts,
    const int* __restrict__ offsets,
    unsigned short* __restrict__ partial,
    int hc0, int Hc) {
  int b, tile;
  if (!decode_bt(blockIdx.x, b, tile)) return;
  int cnt = counts[b];
  int base = tile * MT;
  if (base >= cnt) return;
  int off = offsets[b];

  __shared__ __align__(16) unsigned short a_lds[MT * BS_];
  __shared__ __align__(16) char b_lds[2][16384];
  int tid = threadIdx.x;
  int wv = tid >> 6, lane = tid & 63;
  int lo = lane & 15, hi = lane >> 4;

  for (int i = tid; i < MT * BS_ / 8; i += 256) {
    int t = i >> 4, cb = i & 15;
    int g = base + t;
    uint4 v = make_uint4(0, 0, 0, 0);
    if (g < cnt) v = *(const uint4*)(actw + (size_t)(off + g) * BS_ + cb * 8);
    *(uint4*)(&a_lds[t * BS_ + ((cb ^ (t & 7)) << 3)]) = v;
  }
  __syncthreads();

  bf16x8 Bf[4][4];
#pragma unroll
  for (int kst = 0; kst < 4; kst++)
#pragma unroll
    for (int sf = 0; sf < 4; sf++) {
      int t = sf * 16 + lo, cb = kst * 4 + hi;
      Bf[kst][sf] = ld8(&a_lds[t * BS_ + ((cb ^ (t & 7)) << 3)]);
    }

  const unsigned short* db = dwb + (size_t)b * H_ * BS_;
  int rs = tid >> 4;
  int jc = tid & 15;
  {
    const unsigned short* d0 = db + (size_t)hc0 * BS_;
#pragma unroll
    for (int s = 0; s < 4; s++) {
      int r = s * 16 + rs;
      int j = jc ^ (r & 15);
      gl16(d0 + (size_t)r * BS_ + j * 8, b_lds[0] + s * 4096 + wv * 1024);
    }
  }
  __syncthreads();

  int nit = Hc >> 6;
  int cur = 0;
  for (int it = 0; it < nit; it++) {
    if (it + 1 < nit) {
      const unsigned short* dn = db + (size_t)(hc0 + (it + 1) * 64) * BS_;
#pragma unroll
      for (int s = 0; s < 4; s++) {
        int r = s * 16 + rs;
        int j = jc ^ (r & 15);
        gl16(dn + (size_t)r * BS_ + j * 8, b_lds[cur ^ 1] + s * 4096 + wv * 1024);
      }
    }
    f32x4 acc[4] = {};
    int rl = wv * 16 + lo;
#pragma unroll
    for (int kst = 0; kst < 4; kst++) {
      int cb = kst * 4 + hi;
      bf16x8 Aw = lds8(b_lds[cur] + (rl * 16 + (cb ^ lo)) * 16);
#pragma unroll
      for (int sf = 0; sf < 4; sf++)
        acc[sf] = __builtin_amdgcn_mfma_f32_16x16x32_bf16(Aw, Bf[kst][sf], acc[sf], 0, 0, 0);
    }
    int hrel = it * 64 + wv * 16 + hi * 4;
#pragma unroll
    for (int sf = 0; sf < 4; sf++) {
      int g = base + sf * 16 + lo;
      if (g < cnt) {
        uint2 pk;
        pk.x = (unsigned int)f2bf(acc[sf][0]) | ((unsigned int)f2bf(acc[sf][1]) << 16);
        pk.y = (unsigned int)f2bf(acc[sf][2]) | ((unsigned int)f2bf(acc[sf][3]) << 16);
        *(uint2*)(partial + (size_t)(off + g) * Hc + hrel) = pk;
      }
    }
    __syncthreads();
    cur ^= 1;
  }
}

// ---------------- reduce ---------------------------------------------------
__global__ __launch_bounds__(256) void reduce_kernel(
    const unsigned short* __restrict__ partial,
    const int* __restrict__ inv,
    const float* __restrict__ cbias,
    float* __restrict__ out, int hc0, int Hc) {
  int wv = threadIdx.x >> 6, l = threadIdx.x & 63;
  int n = blockIdx.x * 4 + wv;
  int rows[K_];
#pragma unroll
  for (int k = 0; k < K_; k++) rows[k] = inv[n * K_ + k];
  for (int c0w = 0; c0w < Hc; c0w += 512) {
    int cw = c0w + l * 8;
    if (cw >= Hc) continue;
    float a[8] = {0.f, 0.f, 0.f, 0.f, 0.f, 0.f, 0.f, 0.f};
#pragma unroll
    for (int k = 0; k < K_; k++) {
      uint4 v = *(const uint4*)(partial + (size_t)rows[k] * Hc + cw);
      unsigned int w0 = v.x, w1 = v.y, w2 = v.z, w3 = v.w;
      a[0] += __uint_as_float(w0 << 16); a[1] += __uint_as_float(w0 & 0xFFFF0000u);
      a[2] += __uint_as_float(w1 << 16); a[3] += __uint_as_float(w1 & 0xFFFF0000u);
      a[4] += __uint_as_float(w2 << 16); a[5] += __uint_as_float(w2 & 0xFFFF0000u);
      a[6] += __uint_as_float(w3 << 16); a[7] += __uint_as_float(w3 & 0xFFFF0000u);
    }
    int h = hc0 + cw;
    float4 c0 = *(const float4*)(cbias + h);
    float4 c1 = *(const float4*)(cbias + h + 4);
    float4 o0 = make_float4(a[0] + c0.x, a[1] + c0.y, a[2] + c0.z, a[3] + c0.w);
    float4 o1 = make_float4(a[4] + c1.x, a[5] + c1.y, a[6] + c1.z, a[7] + c1.w);
    *(float4*)(out + (size_t)n * H_ + h) = o0;
    *(float4*)(out + (size_t)n * H_ + h + 4) = o1;
  }
}

// ---------------- launch ---------------------------------------------------
extern "C" void kernel_launch(void* const* d_in, const int* in_sizes, int n_in,
                              void* d_out, int out_size, void* d_ws, size_t ws_size,
                              hipStream_t stream) {
  const float* x       = (const float*)d_in[0];
  const int*   aidx    = (const int*)d_in[1];
  const float* score   = (const float*)d_in[2];
  const float* gate_w  = (const float*)d_in[3];
  const float* up_w    = (const float*)d_in[4];
  const float* down_w  = (const float*)d_in[5];
  const float* enc_w   = (const float*)d_in[6];
  const float* enc_b   = (const float*)d_in[7];
  const float* decoder = (const float*)d_in[8];
  const float* bbias   = (const float*)d_in[9];
  const float* cbias   = (const float*)d_in[10];
  const float* scale   = (const float*)d_in[11];
  float* out = (float*)d_out;

  char* ws = (char*)d_ws;
  const size_t OFF_GWB  = 33554432ull;
  const size_t OFF_UWB  = 56623104ull;
  const size_t OFF_DEC  = 79691776ull;
  const size_t OFF_LATB = 80412672ull;
  const size_t OFF_ENCB = 81461248ull;
  const size_t OFF_WBUF = 81723392ull;
  const size_t OFF_TOK  = 81985536ull;
  const size_t OFF_WT   = 82247680ull;
  const size_t OFF_INV  = 82509824ull;
  const size_t OFF_CNT  = 82771968ull;
  const size_t OFF_ACTW = 82772992ull;
  const size_t BASE_END = 99550208ull;
  const size_t DWB_SZ   = 23068672ull;

  unsigned short* xb   = (unsigned short*)(ws);
  unsigned short* gwb  = (unsigned short*)(ws + OFF_GWB);
  unsigned short* uwb  = (unsigned short*)(ws + OFF_UWB);
  unsigned short* decb = (unsigned short*)(ws + OFF_DEC);
  unsigned short* latb = (unsigned short*)(ws + OFF_LATB);
  unsigned short* ewb  = (unsigned short*)(ws + OFF_ENCB);
  float* w_buf         = (float*)(ws + OFF_WBUF);
  int*   tok_list      = (int*)(ws + OFF_TOK);
  float* wt_list       = (float*)(ws + OFF_WT);
  int*   inv           = (int*)(ws + OFF_INV);
  int*   counts        = (int*)(ws + OFF_CNT);
  int*   offsets       = counts + 64;
  int*   cursors       = counts + 128;
  unsigned short* actw = (unsigned short*)(ws + OFF_ACTW);

  int Hc; unsigned short* dwb; unsigned short* partial; bool early_down;
  if      (ws_size >= BASE_END + DWB_SZ + 131072ull * 512) Hc = 512;
  else if (ws_size >= BASE_END + DWB_SZ + 131072ull * 256) Hc = 256;
  else Hc = 0;
  if (Hc) {
    early_down = true;
    dwb = (unsigned short*)(ws + BASE_END);
    partial = (unsigned short*)(ws + BASE_END + DWB_SZ);
  } else {
    early_down = false;
    Hc = 256;
    dwb = gwb;
    partial = (unsigned short*)ws;
  }
  int nch = H_ / Hc;

  cvt_xgu<<<2048, 256, 0, stream>>>(x, gate_w, up_w, enc_w, xb, gwb, uwb, ewb);
  cvt_dec<<<(NB_ * BS_ * R_ + 255) / 256, 256, 0, stream>>>(decoder, decb);
  if (early_down) cvt_down<<<2048, 256, 0, stream>>>(down_w, dwb);
  zero_counts<<<1, 64, 0, stream>>>(counts);
  prep_kernel<<<N_ / 256, 256, 0, stream>>>(score, aidx, w_buf, counts);
  scan_kernel<<<1, 64, 0, stream>>>(counts, offsets, cursors);
  fill_kernel<<<N_ / 256, 256, 0, stream>>>(aidx, w_buf, cursors, tok_list, wt_list, inv);
  latent_mfma<<<N_ / 64, 256, 0, stream>>>(xb, ewb, enc_b, latb);
  gateup_kernel<<<GRID_AB, 256, 0, stream>>>(xb, gwb, uwb, latb, decb, bbias, scale,
                                             counts, offsets, tok_list, wt_list, actw);
  if (!early_down) cvt_down<<<2048, 256, 0, stream>>>(down_w, dwb);
  for (int c = 0; c < nch; c++) {
    down_kernel<<<GRID_AB, 256, 0, stream>>>(actw, dwb, counts, offsets, partial, c * Hc, Hc);
    reduce_kernel<<<N_ / 4, 256, 0, stream>>>(partial, inv, cbias, out, c * Hc, Hc);
  }
}